// Round 14
// baseline (1619.654 us; speedup 1.0000x reference)
//
#include <hip/hip_runtime.h>
#include <hip/hip_bf16.h>
#include <math.h>

#define LAYERS 6
#define BB 4
#define TT 1024
#define EE 768
#define HH 12
#define HS 64
#define VV 32000
#define FFD 3072
#define MROWS (BB * TT)   // 4096
#define QS (3 * EE)       // 2304, fused qkv row stride
#define KVB 64
#define QBLK 128
#define NPART (VV / 256)  // 125 LSE partial blocks per row

typedef __attribute__((ext_vector_type(8))) short bf16x8_t;
typedef __attribute__((ext_vector_type(4))) float f32x4_t;

// ---------------- helpers ----------------
__device__ __forceinline__ float wave_sum(float v) {
#pragma unroll
    for (int o = 32; o > 0; o >>= 1) v += __shfl_xor(v, o);
    return v;
}
__device__ __forceinline__ float wave_max(float v) {
#pragma unroll
    for (int o = 32; o > 0; o >>= 1) v = fmaxf(v, __shfl_xor(v, o));
    return v;
}
__device__ __forceinline__ float block_sum256(float v, float* red) {
    v = wave_sum(v);
    int tid = threadIdx.x;
    if ((tid & 63) == 0) red[tid >> 6] = v;
    __syncthreads();
    float r = red[0] + red[1] + red[2] + red[3];
    __syncthreads();
    return r;
}
__device__ __forceinline__ float block_max256(float v, float* red) {
    v = wave_max(v);
    int tid = threadIdx.x;
    if ((tid & 63) == 0) red[tid >> 6] = v;
    __syncthreads();
    float r = fmaxf(fmaxf(red[0], red[1]), fmaxf(red[2], red[3]));
    __syncthreads();
    return r;
}

__device__ __forceinline__ void gload_lds16(const void* g, void* l) {
    __builtin_amdgcn_global_load_lds((const __attribute__((address_space(1))) void*)g,
                                     (__attribute__((address_space(3))) void*)l, 16, 0, 0);
}

// pack two f32 -> u32 of 2 bf16 (lo at low address)
__device__ __forceinline__ unsigned pk2bf(float lo, float hi) {
    __hip_bfloat162 h2 = __float22bfloat162_rn(make_float2(lo, hi));
    return *reinterpret_cast<unsigned*>(&h2);
}

// ---------------- embedding: 4 rows/block, wave per row, float4 ----------------
__global__ __launch_bounds__(256) void embed4_k(const int* __restrict__ idx,
                                                const float* __restrict__ tok,
                                                const float* __restrict__ pos,
                                                float* __restrict__ x) {
    int row = blockIdx.x * 4 + (threadIdx.x >> 6);
    int lane = threadIdx.x & 63;
    int t = row & (TT - 1);
    int token = idx[row];
    const float4* te = (const float4*)(tok + (size_t)token * EE);
    const float4* pe = (const float4*)(pos + (size_t)t * EE);
    float4* xr = (float4*)(x + (size_t)row * EE);
#pragma unroll
    for (int j = 0; j < 3; ++j) {
        int i = j * 64 + lane;
        float4 a = te[i], b = pe[i];
        xr[i] = make_float4(a.x + b.x, a.y + b.y, a.z + b.z, a.w + b.w);
    }
}

// ---------------- LayerNorm: wave per row, register-resident, fp32->bf16 -------
__global__ __launch_bounds__(256) void ln4_k(const float* __restrict__ x,
                                             const float* __restrict__ g,
                                             const float* __restrict__ b,
                                             __hip_bfloat16* __restrict__ out) {
    int row = blockIdx.x * 4 + (threadIdx.x >> 6);
    int lane = threadIdx.x & 63;
    const float4* xr = (const float4*)(x + (size_t)row * EE);
    float4 v[3];
    float s = 0.f;
#pragma unroll
    for (int j = 0; j < 3; ++j) {
        v[j] = xr[j * 64 + lane];
        s += v[j].x + v[j].y + v[j].z + v[j].w;
    }
    s = wave_sum(s);
    float m = s * (1.0f / EE);
    float vs = 0.f;
#pragma unroll
    for (int j = 0; j < 3; ++j) {
        float d0 = v[j].x - m, d1 = v[j].y - m, d2 = v[j].z - m, d3 = v[j].w - m;
        vs += d0 * d0 + d1 * d1 + d2 * d2 + d3 * d3;
    }
    vs = wave_sum(vs);
    float rstd = rsqrtf(vs * (1.0f / EE) + 1e-5f);
    const float4* g4 = (const float4*)g;
    const float4* b4 = (const float4*)b;
    uint2* orow = (uint2*)(out + (size_t)row * EE);
#pragma unroll
    for (int j = 0; j < 3; ++j) {
        int i = j * 64 + lane;
        float4 gg = g4[i], bb = b4[i];
        float n0 = (v[j].x - m) * rstd * gg.x + bb.x;
        float n1 = (v[j].y - m) * rstd * gg.y + bb.y;
        float n2 = (v[j].z - m) * rstd * gg.z + bb.z;
        float n3 = (v[j].w - m) * rstd * gg.w + bb.w;
        orow[i] = make_uint2(pk2bf(n0, n1), pk2bf(n2, n3));
    }
}

// ---------------- batched transpose-convert: W fp32 [R,C] -> WT bf16 [C,R] ------
__global__ __launch_bounds__(256) void tconv_b_k(const float* __restrict__ W,
                                                 __hip_bfloat16* __restrict__ WT,
                                                 int R, int C,
                                                 size_t wstride, size_t tstride) {
    __shared__ float t[32][33];
    const float* Wl = W + (size_t)blockIdx.z * wstride;
    __hip_bfloat16* Tl = WT + (size_t)blockIdx.z * tstride;
    int c0 = blockIdx.x * 32, r0 = blockIdx.y * 32;
    int tx = threadIdx.x & 31, ty = threadIdx.x >> 5;
#pragma unroll
    for (int i = 0; i < 4; ++i)
        t[ty + 8 * i][tx] = Wl[(size_t)(r0 + ty + 8 * i) * C + c0 + tx];
    __syncthreads();
#pragma unroll
    for (int i = 0; i < 4; ++i)
        Tl[(size_t)(c0 + ty + 8 * i) * R + r0 + tx] = __float2bfloat16(t[tx][ty + 8 * i]);
}

// ---------------- MFMA GEMM (m97 structure, MI*32 x 128 tile, BK=32) -----------
template <bool BIAS, bool RELU, bool ACCUM, bool OBF16, int MI>
__global__ __launch_bounds__(256) void mgemm_k(const __hip_bfloat16* __restrict__ A,
                                               const __hip_bfloat16* __restrict__ BT,
                                               const float* __restrict__ bias,
                                               void* __restrict__ Cv,
                                               int M, int N, int K, int ntn) {
    __shared__ __align__(16) short As[MI * 32 * 32];
    __shared__ __align__(16) short Bs[128 * 32];

    int nwg = gridDim.x;
    int bid = blockIdx.x;
    int cpx = nwg >> 3;
    int swz = (bid & 7) * cpx + (bid >> 3);
    int tm = swz / ntn, tn = swz - tm * ntn;
    int m0 = tm * (MI * 32), n0 = tn * 128;

    int tid = threadIdx.x;
    int lane = tid & 63;
    int wave = tid >> 6;
    int wr = wave >> 1, wc = wave & 1;

    f32x4_t acc[MI][4];
#pragma unroll
    for (int i = 0; i < MI; ++i)
#pragma unroll
        for (int j = 0; j < 4; ++j)
#pragma unroll
            for (int r = 0; r < 4; ++r) acc[i][j][r] = 0.f;

    const short* Ag = (const short*)A;
    const short* Bg = (const short*)BT;
    const int arow0 = tid >> 2;
    const int arow1 = (tid + 256) >> 2;
    const int acol = (tid & 3) * 8;

    const int fr = lane & 15;
    const int kg = (lane >> 4) * 8;

    for (int k0 = 0; k0 < K; k0 += 32) {
        gload_lds16(Ag + (size_t)(m0 + arow0) * K + k0 + acol, &As[tid * 8]);
        if (MI == 4)
            gload_lds16(Ag + (size_t)(m0 + arow1) * K + k0 + acol, &As[(tid + 256) * 8]);
        gload_lds16(Bg + (size_t)(n0 + arow0) * K + k0 + acol, &Bs[tid * 8]);
        gload_lds16(Bg + (size_t)(n0 + arow1) * K + k0 + acol, &Bs[(tid + 256) * 8]);
        __syncthreads();

        bf16x8_t af[MI], bq[4];
#pragma unroll
        for (int mi = 0; mi < MI; ++mi)
            af[mi] = *(const bf16x8_t*)&As[(wr * (MI * 16) + mi * 16 + fr) * 32 + kg];
#pragma unroll
        for (int ni = 0; ni < 4; ++ni)
            bq[ni] = *(const bf16x8_t*)&Bs[(wc * 64 + ni * 16 + fr) * 32 + kg];
#pragma unroll
        for (int mi = 0; mi < MI; ++mi)
#pragma unroll
            for (int ni = 0; ni < 4; ++ni)
                acc[mi][ni] = __builtin_amdgcn_mfma_f32_16x16x32_bf16(af[mi], bq[ni], acc[mi][ni], 0, 0, 0);
        __syncthreads();
    }

    float bvec[4];
    if (BIAS) {
#pragma unroll
        for (int ni = 0; ni < 4; ++ni) bvec[ni] = bias[n0 + wc * 64 + ni * 16 + fr];
    }
    const int rbase = m0 + wr * (MI * 16) + (lane >> 4) * 4;
    const int cbase = n0 + wc * 64 + fr;
#pragma unroll
    for (int mi = 0; mi < MI; ++mi) {
#pragma unroll
        for (int ni = 0; ni < 4; ++ni) {
#pragma unroll
            for (int r = 0; r < 4; ++r) {
                int row = rbase + mi * 16 + r;
                int col = cbase + ni * 16;
                float v = acc[mi][ni][r];
                if (BIAS) v += bvec[ni];
                if (RELU) v = fmaxf(v, 0.f);
                size_t off = (size_t)row * N + col;
                if (OBF16) {
                    ((__hip_bfloat16*)Cv)[off] = __float2bfloat16(v);
                } else {
                    float* Cf = (float*)Cv;
                    if (ACCUM) Cf[off] += v; else Cf[off] = v;
                }
            }
        }
    }
}

// ---------------- 256x256 8-phase MFMA GEMM (proven r5/r8 form, BK=64) ---------
__device__ __forceinline__ bf16x8_t ldsrd256(const short* base, int row, int colb) {
    return *(const bf16x8_t*)((const char*)base + ((row << 7) + (colb ^ ((row & 7) << 4))));
}

template <bool BIAS, bool RELU, bool OBF16, bool LSE>
__global__ __launch_bounds__(512, 2) void mgemm256_k(const __hip_bfloat16* __restrict__ A,
                                                     const __hip_bfloat16* __restrict__ BT,
                                                     const float* __restrict__ bias,
                                                     void* __restrict__ Cv,
                                                     int M, int N, int K,
                                                     int ntn, int npart,
                                                     float2* __restrict__ partials) {
    __shared__ __align__(16) short lds[2][2][2][8192];   // [buf][A/B][half][128*64]

    const int nwg = gridDim.x;
    const int bid = blockIdx.x;
    const int cpx = nwg >> 3;
    const int swz = (bid & 7) * cpx + (bid >> 3);
    const int tm = swz / ntn, tn = swz - tm * ntn;
    const int m0 = tm * 256, n0 = tn * 256;

    const int tid = threadIdx.x;
    const int lane = tid & 63;
    const int wave = tid >> 6;
    const int wm = wave >> 2;       // 0..1
    const int wn = wave & 3;        // 0..3
    const int fr = lane & 15;
    const int hi4 = lane >> 4;

    const short* Ag = (const short*)A;
    const short* Bg = (const short*)BT;
    const int nt = K >> 6;          // 12

    auto stage_half = [&](const short* g, int grow0, int k0, short* lbase) {
#pragma unroll
        for (int sub = 0; sub < 2; ++sub) {
            int d = sub * 8192 + tid * 16;
            int row = d >> 7;
            int cb = d & 127;
            int col = (cb ^ ((row & 7) << 4)) >> 1;
            gload_lds16(g + (size_t)(grow0 + row) * K + k0 + col, (char*)lbase + d);
        }
    };

    f32x4_t acc[2][2][4][2];
#pragma unroll
    for (int ah = 0; ah < 2; ++ah)
#pragma unroll
        for (int s = 0; s < 2; ++s)
#pragma unroll
            for (int mi = 0; mi < 4; ++mi)
#pragma unroll
                for (int ni = 0; ni < 2; ++ni)
#pragma unroll
                    for (int r = 0; r < 4; ++r) acc[ah][s][mi][ni][r] = 0.f;

    stage_half(Ag, m0 + 0,   0,  &lds[0][0][0][0]);
    stage_half(Bg, n0 + 0,   0,  &lds[0][1][0][0]);
    stage_half(Ag, m0 + 128, 0,  &lds[0][0][1][0]);
    stage_half(Bg, n0 + 128, 0,  &lds[0][1][1][0]);
    stage_half(Ag, m0 + 0,   64, &lds[1][0][0][0]);
    stage_half(Bg, n0 + 0,   64, &lds[1][1][0][0]);
    asm volatile("s_waitcnt vmcnt(4)" ::: "memory");
    __builtin_amdgcn_s_barrier();

    for (int t = 0; t < nt; ++t) {
        const int c = t & 1, o = c ^ 1;
        bf16x8_t a[4][2];
#pragma unroll
        for (int p = 0; p < 4; ++p) {
            const int ah = p >> 1, s = p & 1;
            if (s == 0) {
#pragma unroll
                for (int mi = 0; mi < 4; ++mi)
#pragma unroll
                    for (int kk = 0; kk < 2; ++kk)
                        a[mi][kk] = ldsrd256(&lds[c][0][ah][0],
                                             wm * 64 + mi * 16 + fr, kk * 64 + hi4 * 16);
            }
            bf16x8_t b[2][2];
#pragma unroll
            for (int ni = 0; ni < 2; ++ni)
#pragma unroll
                for (int kk = 0; kk < 2; ++kk)
                    b[ni][kk] = ldsrd256(&lds[c][1][s][0],
                                         wn * 32 + ni * 16 + fr, kk * 64 + hi4 * 16);
            if (p == 0 && t + 1 < nt) stage_half(Ag, m0 + 128, (t + 1) * 64, &lds[o][0][1][0]);
            if (p == 1 && t + 1 < nt) stage_half(Bg, n0 + 128, (t + 1) * 64, &lds[o][1][1][0]);
            if (p == 2 && t + 2 < nt) stage_half(Ag, m0 + 0,   (t + 2) * 64, &lds[c][0][0][0]);
            if (p == 3 && t + 2 < nt) stage_half(Bg, n0 + 0,   (t + 2) * 64, &lds[c][1][0][0]);
            if (p == 3) {
                if (t < nt - 2)       asm volatile("s_waitcnt vmcnt(4)" ::: "memory");
                else if (t == nt - 2) asm volatile("s_waitcnt vmcnt(0)" ::: "memory");
            }
            __builtin_amdgcn_s_barrier();
            asm volatile("s_waitcnt lgkmcnt(0)" ::: "memory");
            __builtin_amdgcn_sched_barrier(0);
            __builtin_amdgcn_s_setprio(1);
#pragma unroll
            for (int mi = 0; mi < 4; ++mi)
#pragma unroll
                for (int ni = 0; ni < 2; ++ni)
#pragma unroll
                    for (int kk = 0; kk < 2; ++kk)
                        acc[ah][s][mi][ni] = __builtin_amdgcn_mfma_f32_16x16x32_bf16(
                            a[mi][kk], b[ni][kk], acc[ah][s][mi][ni], 0, 0, 0);
            __builtin_amdgcn_s_setprio(0);
            __builtin_amdgcn_s_barrier();
        }
    }

    float bv[2][2];
    if (BIAS) {
#pragma unroll
        for (int s = 0; s < 2; ++s)
#pragma unroll
            for (int ni = 0; ni < 2; ++ni)
                bv[s][ni] = bias[n0 + s * 128 + wn * 32 + ni * 16 + fr];
    }
    float2* red = (float2*)&lds[0][0][0][0];
#pragma unroll
    for (int ah = 0; ah < 2; ++ah) {
#pragma unroll
        for (int mi = 0; mi < 4; ++mi) {
#pragma unroll
            for (int r = 0; r < 4; ++r) {
                const int rb = ah * 128 + wm * 64 + mi * 16 + hi4 * 4 + r;
                const size_t grow = (size_t)(m0 + rb);
                float v[2][2];
#pragma unroll
                for (int s = 0; s < 2; ++s)
#pragma unroll
                    for (int ni = 0; ni < 2; ++ni) {
                        float vv = acc[ah][s][mi][ni][r];
                        if (BIAS) vv += bv[s][ni];
                        if (RELU) vv = fmaxf(vv, 0.f);
                        v[s][ni] = vv;
                        size_t off = grow * N + n0 + s * 128 + wn * 32 + ni * 16 + fr;
                        if (OBF16) ((__hip_bfloat16*)Cv)[off] = __float2bfloat16(vv);
                        else       ((float*)Cv)[off] = vv;
                    }
                if (LSE) {
                    float mx = fmaxf(fmaxf(v[0][0], v[0][1]), fmaxf(v[1][0], v[1][1]));
#pragma unroll
                    for (int off2 = 1; off2 < 16; off2 <<= 1) mx = fmaxf(mx, __shfl_xor(mx, off2));
                    float sm = 0.f;
#pragma unroll
                    for (int s = 0; s < 2; ++s)
#pragma unroll
                        for (int ni = 0; ni < 2; ++ni) sm += __expf(v[s][ni] - mx);
#pragma unroll
                    for (int off2 = 1; off2 < 16; off2 <<= 1) sm += __shfl_xor(sm, off2);
                    if (fr == 0) red[rb * 4 + wn] = make_float2(mx, sm);
                }
            }
        }
    }
    if (LSE) {
        __syncthreads();
        if (tid < 256) {
            float2 p0 = red[tid * 4 + 0], p1 = red[tid * 4 + 1];
            float2 p2 = red[tid * 4 + 2], p3 = red[tid * 4 + 3];
            float M2 = fmaxf(fmaxf(p0.x, p1.x), fmaxf(p2.x, p3.x));
            float L2 = p0.y * __expf(p0.x - M2) + p1.y * __expf(p1.x - M2) +
                       p2.y * __expf(p2.x - M2) + p3.y * __expf(p3.x - M2);
            partials[(size_t)(m0 + tid) * npart + tn] = make_float2(M2, L2);
        }
    }
}

// ---------------- MFMA flash attention: swapped QK^T + T14 + T13 + T5 ----------
__global__ __launch_bounds__(256) void fattn_k(const __hip_bfloat16* __restrict__ qkv,
                                               __hip_bfloat16* __restrict__ o) {
    __shared__ short Ks[KVB * HS];
    __shared__ short Vt[HS * KVB];
    __shared__ short Pl[4 * 32 * KVB];

    const int bh = blockIdx.x;
    const int hh = bh % HH;
    const int bI = bh / HH;
    const int qt = (TT / QBLK - 1) - blockIdx.y;   // heavy tiles first
    const int q0 = qt * QBLK;

    const int tid = threadIdx.x;
    const int lane = tid & 63;
    const int wave = tid >> 6;
    const int fr = lane & 15;
    const int hi4 = lane >> 4;

    const size_t rowbase = (size_t)bI * TT;
    const int wq0 = q0 + wave * 32;

    bf16x8_t qf[2][2];
#pragma unroll
    for (int mi = 0; mi < 2; ++mi)
#pragma unroll
        for (int kc = 0; kc < 2; ++kc) {
            const short* src = (const short*)qkv +
                (rowbase + wq0 + mi * 16 + fr) * QS + hh * HS + kc * 32 + hi4 * 8;
            bf16x8_t v = *(const bf16x8_t*)src;
#pragma unroll
            for (int e = 0; e < 8; ++e) {
                float f = __uint_as_float(((unsigned)(unsigned short)v[e]) << 16) * 0.125f;
                v[e] = (short)(__float_as_uint(f) >> 16);
            }
            qf[mi][kc] = v;
        }

    f32x4_t oa[2][4];
    float m_r[2], l_r[2];
#pragma unroll
    for (int mi = 0; mi < 2; ++mi) {
        m_r[mi] = -INFINITY;
        l_r[mi] = 0.f;
#pragma unroll
        for (int nd = 0; nd < 4; ++nd)
#pragma unroll
            for (int r = 0; r < 4; ++r) oa[mi][nd][r] = 0.f;
    }

    const int skey = tid >> 2;
    const int sd0 = (tid & 3) * 16;
    const int niter = 2 * (qt + 1);

    uint4 ka, kb2, va, vb2;
    {
        const short* kg = (const short*)qkv + (rowbase + skey) * QS + EE + hh * HS + sd0;
        ka = *(const uint4*)kg; kb2 = *(const uint4*)(kg + 8);
        const short* vg = (const short*)qkv + (rowbase + skey) * QS + 2 * EE + hh * HS + sd0;
        va = *(const uint4*)vg; vb2 = *(const uint4*)(vg + 8);
    }

    for (int it = 0; it < niter; ++it) {
        __syncthreads();
        {
            const int rs = (skey & 7) << 4;
            char* kbp = (char*)Ks;
            *(uint4*)(kbp + ((skey * 128 + sd0 * 2) ^ rs)) = ka;
            *(uint4*)(kbp + ((skey * 128 + sd0 * 2 + 16) ^ rs)) = kb2;

            char* vbp = (char*)Vt;
            const short* vs0 = (const short*)&va;
#pragma unroll
            for (int e = 0; e < 8; ++e) {
                int dd = sd0 + e;
                *(short*)(vbp + ((dd * 128 + skey * 2) ^ ((dd & 7) << 4))) = vs0[e];
            }
            const short* vs1 = (const short*)&vb2;
#pragma unroll
            for (int e = 0; e < 8; ++e) {
                int dd = sd0 + 8 + e;
                *(short*)(vbp + ((dd * 128 + skey * 2) ^ ((dd & 7) << 4))) = vs1[e];
            }
        }
        __syncthreads();

        if (it + 1 < niter) {
            const int kvn = (it + 1) * KVB;
            const short* kg = (const short*)qkv + (rowbase + kvn + skey) * QS + EE + hh * HS + sd0;
            ka = *(const uint4*)kg; kb2 = *(const uint4*)(kg + 8);
            const short* vg = (const short*)qkv + (rowbase + kvn + skey) * QS + 2 * EE + hh * HS + sd0;
            va = *(const uint4*)vg; vb2 = *(const uint4*)(vg + 8);
        }

        const int kv0 = it * KVB;

        f32x4_t sa[2][4];
#pragma unroll
        for (int mi = 0; mi < 2; ++mi)
#pragma unroll
            for (int ni = 0; ni < 4; ++ni)
#pragma unroll
                for (int r = 0; r < 4; ++r) sa[mi][ni][r] = 0.f;
        __builtin_amdgcn_s_setprio(1);
#pragma unroll
        for (int kc = 0; kc < 2; ++kc) {
            bf16x8_t kf[4];
#pragma unroll
            for (int ni = 0; ni < 4; ++ni) {
                int krow = ni * 16 + fr;
                kf[ni] = *(const bf16x8_t*)((char*)Ks +
                    ((krow * 128 + (kc * 32 + hi4 * 8) * 2) ^ ((krow & 7) << 4)));
            }
#pragma unroll
            for (int mi = 0; mi < 2; ++mi)
#pragma unroll
                for (int ni = 0; ni < 4; ++ni)
                    sa[mi][ni] = __builtin_amdgcn_mfma_f32_16x16x32_bf16(kf[ni], qf[mi][kc], sa[mi][ni], 0, 0, 0);
        }
        __builtin_amdgcn_s_setprio(0);

        if (kv0 + KVB - 1 > wq0) {
#pragma unroll
            for (int mi = 0; mi < 2; ++mi) {
                int qrow = wq0 + mi * 16 + fr;
#pragma unroll
                for (int ni = 0; ni < 4; ++ni)
#pragma unroll
                    for (int r = 0; r < 4; ++r) {
                        int key = kv0 + ni * 16 + hi4 * 4 + r;
                        if (key > qrow) sa[mi][ni][r] = -1e30f;
                    }
            }
        }

        char* Pw = (char*)Pl + wave * 4096;
#pragma unroll
        for (int mi = 0; mi < 2; ++mi) {
            float mx = sa[mi][0][0];
#pragma unroll
            for (int ni = 0; ni < 4; ++ni)
#pragma unroll
                for (int r = 0; r < 4; ++r) mx = fmaxf(mx, sa[mi][ni][r]);
            mx = fmaxf(mx, __shfl_xor(mx, 16));
            mx = fmaxf(mx, __shfl_xor(mx, 32));
            // T13 defer-max: skip rescale while tile max stays within 8 of running max
            if (!__all(mx <= m_r[mi] + 8.0f)) {
                float mnew = fmaxf(m_r[mi], mx);
                float al = __expf(m_r[mi] - mnew);
                m_r[mi] = mnew;
                l_r[mi] *= al;
#pragma unroll
                for (int r = 0; r < 4; ++r) {
                    float a_r = __shfl(al, hi4 * 4 + r);
#pragma unroll
                    for (int nd = 0; nd < 4; ++nd) oa[mi][nd][r] *= a_r;
                }
            }
            float ps = 0.f;
#pragma unroll
            for (int ni = 0; ni < 4; ++ni) {
#pragma unroll
                for (int r = 0; r < 4; ++r) {
                    float p = __expf(sa[mi][ni][r] - m_r[mi]);
                    sa[mi][ni][r] = p;
                    ps += p;
                }
                uint2 pw;
                pw.x = pk2bf(sa[mi][ni][0], sa[mi][ni][1]);
                pw.y = pk2bf(sa[mi][ni][2], sa[mi][ni][3]);
                int prow = mi * 16 + fr;
                int cb = ni * 32 + hi4 * 8;
                *(uint2*)(Pw + ((prow * 128 + cb) ^ ((prow & 7) << 4))) = pw;
            }
            ps += __shfl_xor(ps, 16);
            ps += __shfl_xor(ps, 32);
            l_r[mi] += ps;
        }

        __builtin_amdgcn_s_setprio(1);
#pragma unroll
        for (int kc = 0; kc < 2; ++kc) {
            bf16x8_t pf[2], vf[4];
#pragma unroll
            for (int mi = 0; mi < 2; ++mi) {
                int prow = mi * 16 + fr;
                pf[mi] = *(const bf16x8_t*)(Pw +
                    ((prow * 128 + (kc * 32 + hi4 * 8) * 2) ^ ((prow & 7) << 4)));
            }
#pragma unroll
            for (int nd = 0; nd < 4; ++nd) {
                int vrow = nd * 16 + fr;
                vf[nd] = *(const bf16x8_t*)((char*)Vt +
                    ((vrow * 128 + (kc * 32 + hi4 * 8) * 2) ^ ((vrow & 7) << 4)));
            }
#pragma unroll
            for (int mi = 0; mi < 2; ++mi)
#pragma unroll
                for (int nd = 0; nd < 4; ++nd)
                    oa[mi][nd] = __builtin_amdgcn_mfma_f32_16x16x32_bf16(pf[mi], vf[nd], oa[mi][nd], 0, 0, 0);
        }
        __builtin_amdgcn_s_setprio(0);
    }

#pragma unroll
    for (int mi = 0; mi < 2; ++mi)
#pragma unroll
        for (int r = 0; r < 4; ++r) {
            float lr = __shfl(l_r[mi], hi4 * 4 + r);
            float inv = 1.0f / lr;
            int row = wq0 + mi * 16 + hi4 * 4 + r;
            __hip_bfloat16* orow = o + (rowbase + row) * EE + hh * HS;
#pragma unroll
            for (int nd = 0; nd < 4; ++nd)
                orow[nd * 16 + fr] = __float2bfloat16(oa[mi][nd][r] * inv);
        }
}

// ---------------- loss: merge per-block LSE partials ----------------
__global__ __launch_bounds__(256) void rowloss2_k(const float2* __restrict__ partials,
                                                  const float* __restrict__ logits,
                                                  const int* __restrict__ targets,
                                                  float* __restrict__ rowloss, int ntn) {
    __shared__ float red[4];
    int row = blockIdx.x;
    int tid = threadIdx.x;
    float m = -INFINITY, l = 0.f;
    if (tid < ntn) {
        float2 p = partials[(size_t)row * ntn + tid];
        m = p.x; l = p.y;
    }
    float mg = block_max256(m, red);
    float s = (tid < ntn) ? l * __expf(m - mg) : 0.f;
    s = block_sum256(s, red);
    if (tid == 0)
        rowloss[row] = mg + logf(s) - logits[(size_t)row * VV + targets[row]];
}

__global__ __launch_bounds__(256) void loss_final_k(const float* __restrict__ rowloss,
                                                    float* __restrict__ out) {
    __shared__ float red[4];
    float s = 0.f;
    for (int i = threadIdx.x; i < MROWS; i += 256) s += rowloss[i];
    s = block_sum256(s, red);
    if (threadIdx.x == 0) out[0] = s * (1.0f / MROWS);
}

// ---------------- launcher ----------------
extern "C" void kernel_launch(void* const* d_in, const int* in_sizes, int n_in,
                              void* d_out, int out_size, void* d_ws, size_t ws_size,
                              hipStream_t stream) {
    const int* idx      = (const int*)d_in[0];
    const int* targets  = (const int*)d_in[1];
    const float* tok    = (const float*)d_in[2];
    const float* pos    = (const float*)d_in[3];
    const float* Wq     = (const float*)d_in[4];
    const float* Wk     = (const float*)d_in[5];
    const float* Wv     = (const float*)d_in[6];
    const float* Wp     = (const float*)d_in[7];
    const float* bp     = (const float*)d_in[8];
    const float* W1     = (const float*)d_in[9];
    const float* b1     = (const float*)d_in[10];
    const float* W2     = (const float*)d_in[11];
    const float* b2     = (const float*)d_in[12];
    const float* ln1_g  = (const float*)d_in[13];
    const float* ln1_b  = (const float*)d_in[14];
    const float* ln2_g  = (const float*)d_in[15];
    const float* ln2_b  = (const float*)d_in[16];
    const float* lnf_g  = (const float*)d_in[17];
    const float* lnf_b  = (const float*)d_in[18];
    const float* Wlm    = (const float*)d_in[19];
    const float* blm    = (const float*)d_in[20];

    float* out = (float*)d_out;

    // ---- workspace carve ----
    char* w = (char*)d_ws;
    float* x = (float*)w;                             w += (size_t)MROWS * EE * 4;
    __hip_bfloat16* hbf = (__hip_bfloat16*)w;         w += (size_t)MROWS * EE * 2;
    __hip_bfloat16* qkv = (__hip_bfloat16*)w;         w += (size_t)MROWS * QS * 2;
    __hip_bfloat16* obf = (__hip_bfloat16*)w;         w += (size_t)MROWS * EE * 2;
    __hip_bfloat16* ff1 = (__hip_bfloat16*)w;         w += (size_t)MROWS * FFD * 2;
    float2* partials = (float2*)ff1;                  // aliases ff1: dead by LM-head time
    __hip_bfloat16* wlmT = (__hip_bfloat16*)w;        w += (size_t)VV * EE * 2;
    float* rowloss = (float*)w;                       w += (size_t)MROWS * 4 + 256;
    __hip_bfloat16* wbase = (__hip_bfloat16*)w;       // layer weights from here

    const size_t base_used = (size_t)(w - (char*)d_ws);
    const size_t per_layer_w = ((size_t)QS * EE + (size_t)EE * EE +
                                (size_t)FFD * EE + (size_t)EE * FFD) * 2;
    const bool hoist = ws_size >= base_used + per_layer_w * LAYERS;
    const int nlw = hoist ? LAYERS : 1;

    __hip_bfloat16* qkvwT = wbase;
    __hip_bfloat16* wpT   = qkvwT + (size_t)nlw * QS * EE;
    __hip_bfloat16* w1T   = wpT   + (size_t)nlw * EE * EE;
    __hip_bfloat16* w2T   = w1T   + (size_t)nlw * FFD * EE;

    dim3 blk(256);

    embed4_k<<<MROWS / 4, blk, 0, stream>>>(idx, tok, pos, x);

    if (hoist) {
        tconv_b_k<<<dim3(EE / 32, EE / 32, LAYERS), blk, 0, stream>>>(
            Wq, qkvwT, EE, EE, (size_t)EE * EE, (size_t)QS * EE);
        tconv_b_k<<<dim3(EE / 32, EE / 32, LAYERS), blk, 0, stream>>>(
            Wk, qkvwT + (size_t)EE * EE, EE, EE, (size_t)EE * EE, (size_t)QS * EE);
        tconv_b_k<<<dim3(EE / 32, EE / 32, LAYERS), blk, 0, stream>>>(
            Wv, qkvwT + (size_t)2 * EE * EE, EE, EE, (size_t)EE * EE, (size_t)QS * EE);
        tconv_b_k<<<dim3(EE / 32, EE / 32, LAYERS), blk, 0, stream>>>(
            Wp, wpT, EE, EE, (size_t)EE * EE, (size_t)EE * EE);
        tconv_b_k<<<dim3(FFD / 32, EE / 32, LAYERS), blk, 0, stream>>>(
            W1, w1T, EE, FFD, (size_t)EE * FFD, (size_t)FFD * EE);
        tconv_b_k<<<dim3(EE / 32, FFD / 32, LAYERS), blk, 0, stream>>>(
            W2, w2T, FFD, EE, (size_t)FFD * EE, (size_t)EE * FFD);
    }
    tconv_b_k<<<dim3(VV / 32, EE / 32, 1), blk, 0, stream>>>(Wlm, wlmT, EE, VV, 0, 0);

    for (int l = 0; l < LAYERS; ++l) {
        __hip_bfloat16* qkvwT_l = qkvwT + (hoist ? (size_t)l * QS * EE : 0);
        __hip_bfloat16* wpT_l   = wpT   + (hoist ? (size_t)l * EE * EE : 0);
        __hip_bfloat16* w1T_l   = w1T   + (hoist ? (size_t)l * FFD * EE : 0);
        __hip_bfloat16* w2T_l   = w2T   + (hoist ? (size_t)l * EE * FFD : 0);
        if (!hoist) {
            tconv_b_k<<<dim3(EE / 32, EE / 32, 1), blk, 0, stream>>>(
                Wq + (size_t)l * EE * EE, qkvwT_l, EE, EE, 0, 0);
            tconv_b_k<<<dim3(EE / 32, EE / 32, 1), blk, 0, stream>>>(
                Wk + (size_t)l * EE * EE, qkvwT_l + (size_t)EE * EE, EE, EE, 0, 0);
            tconv_b_k<<<dim3(EE / 32, EE / 32, 1), blk, 0, stream>>>(
                Wv + (size_t)l * EE * EE, qkvwT_l + (size_t)2 * EE * EE, EE, EE, 0, 0);
            tconv_b_k<<<dim3(EE / 32, EE / 32, 1), blk, 0, stream>>>(
                Wp + (size_t)l * EE * EE, wpT_l, EE, EE, 0, 0);
            tconv_b_k<<<dim3(FFD / 32, EE / 32, 1), blk, 0, stream>>>(
                W1 + (size_t)l * EE * FFD, w1T_l, EE, FFD, 0, 0);
            tconv_b_k<<<dim3(EE / 32, FFD / 32, 1), blk, 0, stream>>>(
                W2 + (size_t)l * FFD * EE, w2T_l, FFD, EE, 0, 0);
        }

        ln4_k<<<MROWS / 4, blk, 0, stream>>>(x, ln1_g + l * EE, ln1_b + l * EE, hbf);
        // QKV: MI=2 isolated (grid 1152 = 4.5 blocks/CU vs 576@MI=4 = 2.25)
        mgemm_k<false, false, false, true, 2><<<dim3((MROWS / 64) * (QS / 128)), blk, 0, stream>>>(
            hbf, qkvwT_l, nullptr, qkv, MROWS, QS, EE, QS / 128);
        fattn_k<<<dim3(BB * HH, TT / QBLK), blk, 0, stream>>>(qkv, obf);
        mgemm_k<true, false, true, false, 2><<<dim3((MROWS / 64) * (EE / 128)), blk, 0, stream>>>(
            obf, wpT_l, bp + l * EE, x, MROWS, EE, EE, EE / 128);
        ln4_k<<<MROWS / 4, blk, 0, stream>>>(x, ln2_g + l * EE, ln2_b + l * EE, hbf);
        mgemm_k<true, true, false, true, 4><<<dim3((MROWS / 128) * (FFD / 128)), blk, 0, stream>>>(
            hbf, w1T_l, b1 + l * FFD, ff1, MROWS, FFD, EE, FFD / 128);
        mgemm_k<true, false, true, false, 2><<<dim3((MROWS / 64) * (EE / 128)), blk, 0, stream>>>(
            ff1, w2T_l, b2 + l * EE, x, MROWS, EE, FFD, EE / 128);
    }

    ln4_k<<<MROWS / 4, blk, 0, stream>>>(x, lnf_g, lnf_b, hbf);
    // LM head: proven 256x256 8-phase BK=64 kernel + fused LSE partials
    mgemm256_k<true, false, false, true><<<dim3((MROWS / 256) * (VV / 256)), dim3(512), 0, stream>>>(
        hbf, wlmT, blm, out, MROWS, VV, EE, VV / 256, NPART, partials);

    rowloss2_k<<<MROWS, blk, 0, stream>>>(partials, out, targets, rowloss, NPART);
    loss_final_k<<<1, blk, 0, stream>>>(rowloss, out + (size_t)MROWS * VV);
}

// Round 15
// 1600.554 us; speedup vs baseline: 1.0119x; 1.0119x over previous
//
#include <hip/hip_runtime.h>
#include <hip/hip_bf16.h>
#include <math.h>

#define LAYERS 6
#define BB 4
#define TT 1024
#define EE 768
#define HH 12
#define HS 64
#define VV 32000
#define FFD 3072
#define MROWS (BB * TT)   // 4096
#define QS (3 * EE)       // 2304, fused qkv row stride
#define KVB 64
#define QBLK 128
#define NPART (VV / 256)  // 125 LSE partial blocks per row

typedef __attribute__((ext_vector_type(8))) short bf16x8_t;
typedef __attribute__((ext_vector_type(4))) float f32x4_t;

// ---------------- helpers ----------------
__device__ __forceinline__ float wave_sum(float v) {
#pragma unroll
    for (int o = 32; o > 0; o >>= 1) v += __shfl_xor(v, o);
    return v;
}
__device__ __forceinline__ float wave_max(float v) {
#pragma unroll
    for (int o = 32; o > 0; o >>= 1) v = fmaxf(v, __shfl_xor(v, o));
    return v;
}
__device__ __forceinline__ float block_sum256(float v, float* red) {
    v = wave_sum(v);
    int tid = threadIdx.x;
    if ((tid & 63) == 0) red[tid >> 6] = v;
    __syncthreads();
    float r = red[0] + red[1] + red[2] + red[3];
    __syncthreads();
    return r;
}
__device__ __forceinline__ float block_max256(float v, float* red) {
    v = wave_max(v);
    int tid = threadIdx.x;
    if ((tid & 63) == 0) red[tid >> 6] = v;
    __syncthreads();
    float r = fmaxf(fmaxf(red[0], red[1]), fmaxf(red[2], red[3]));
    __syncthreads();
    return r;
}

__device__ __forceinline__ void gload_lds16(const void* g, void* l) {
    __builtin_amdgcn_global_load_lds((const __attribute__((address_space(1))) void*)g,
                                     (__attribute__((address_space(3))) void*)l, 16, 0, 0);
}

// pack two f32 -> u32 of 2 bf16 (lo at low address)
__device__ __forceinline__ unsigned pk2bf(float lo, float hi) {
    __hip_bfloat162 h2 = __float22bfloat162_rn(make_float2(lo, hi));
    return *reinterpret_cast<unsigned*>(&h2);
}

// ---------------- embedding: 4 rows/block, wave per row, float4 ----------------
__global__ __launch_bounds__(256) void embed4_k(const int* __restrict__ idx,
                                                const float* __restrict__ tok,
                                                const float* __restrict__ pos,
                                                float* __restrict__ x) {
    int row = blockIdx.x * 4 + (threadIdx.x >> 6);
    int lane = threadIdx.x & 63;
    int t = row & (TT - 1);
    int token = idx[row];
    const float4* te = (const float4*)(tok + (size_t)token * EE);
    const float4* pe = (const float4*)(pos + (size_t)t * EE);
    float4* xr = (float4*)(x + (size_t)row * EE);
#pragma unroll
    for (int j = 0; j < 3; ++j) {
        int i = j * 64 + lane;
        float4 a = te[i], b = pe[i];
        xr[i] = make_float4(a.x + b.x, a.y + b.y, a.z + b.z, a.w + b.w);
    }
}

// ---------------- LayerNorm: wave per row, register-resident, fp32->bf16 -------
__global__ __launch_bounds__(256) void ln4_k(const float* __restrict__ x,
                                             const float* __restrict__ g,
                                             const float* __restrict__ b,
                                             __hip_bfloat16* __restrict__ out) {
    int row = blockIdx.x * 4 + (threadIdx.x >> 6);
    int lane = threadIdx.x & 63;
    const float4* xr = (const float4*)(x + (size_t)row * EE);
    float4 v[3];
    float s = 0.f;
#pragma unroll
    for (int j = 0; j < 3; ++j) {
        v[j] = xr[j * 64 + lane];
        s += v[j].x + v[j].y + v[j].z + v[j].w;
    }
    s = wave_sum(s);
    float m = s * (1.0f / EE);
    float vs = 0.f;
#pragma unroll
    for (int j = 0; j < 3; ++j) {
        float d0 = v[j].x - m, d1 = v[j].y - m, d2 = v[j].z - m, d3 = v[j].w - m;
        vs += d0 * d0 + d1 * d1 + d2 * d2 + d3 * d3;
    }
    vs = wave_sum(vs);
    float rstd = rsqrtf(vs * (1.0f / EE) + 1e-5f);
    const float4* g4 = (const float4*)g;
    const float4* b4 = (const float4*)b;
    uint2* orow = (uint2*)(out + (size_t)row * EE);
#pragma unroll
    for (int j = 0; j < 3; ++j) {
        int i = j * 64 + lane;
        float4 gg = g4[i], bb = b4[i];
        float n0 = (v[j].x - m) * rstd * gg.x + bb.x;
        float n1 = (v[j].y - m) * rstd * gg.y + bb.y;
        float n2 = (v[j].z - m) * rstd * gg.z + bb.z;
        float n3 = (v[j].w - m) * rstd * gg.w + bb.w;
        orow[i] = make_uint2(pk2bf(n0, n1), pk2bf(n2, n3));
    }
}

// ---------------- batched transpose-convert: W fp32 [R,C] -> WT bf16 [C,R] ------
__global__ __launch_bounds__(256) void tconv_b_k(const float* __restrict__ W,
                                                 __hip_bfloat16* __restrict__ WT,
                                                 int R, int C,
                                                 size_t wstride, size_t tstride) {
    __shared__ float t[32][33];
    const float* Wl = W + (size_t)blockIdx.z * wstride;
    __hip_bfloat16* Tl = WT + (size_t)blockIdx.z * tstride;
    int c0 = blockIdx.x * 32, r0 = blockIdx.y * 32;
    int tx = threadIdx.x & 31, ty = threadIdx.x >> 5;
#pragma unroll
    for (int i = 0; i < 4; ++i)
        t[ty + 8 * i][tx] = Wl[(size_t)(r0 + ty + 8 * i) * C + c0 + tx];
    __syncthreads();
#pragma unroll
    for (int i = 0; i < 4; ++i)
        Tl[(size_t)(c0 + ty + 8 * i) * R + r0 + tx] = __float2bfloat16(t[tx][ty + 8 * i]);
}

// ---------------- MFMA GEMM (m97 structure, MI*32 x 128 tile, BK=32) -----------
template <bool BIAS, bool RELU, bool ACCUM, bool OBF16, int MI>
__global__ __launch_bounds__(256) void mgemm_k(const __hip_bfloat16* __restrict__ A,
                                               const __hip_bfloat16* __restrict__ BT,
                                               const float* __restrict__ bias,
                                               void* __restrict__ Cv,
                                               int M, int N, int K, int ntn) {
    __shared__ __align__(16) short As[MI * 32 * 32];
    __shared__ __align__(16) short Bs[128 * 32];

    int nwg = gridDim.x;
    int bid = blockIdx.x;
    int cpx = nwg >> 3;
    int swz = (bid & 7) * cpx + (bid >> 3);
    int tm = swz / ntn, tn = swz - tm * ntn;
    int m0 = tm * (MI * 32), n0 = tn * 128;

    int tid = threadIdx.x;
    int lane = tid & 63;
    int wave = tid >> 6;
    int wr = wave >> 1, wc = wave & 1;

    f32x4_t acc[MI][4];
#pragma unroll
    for (int i = 0; i < MI; ++i)
#pragma unroll
        for (int j = 0; j < 4; ++j)
#pragma unroll
            for (int r = 0; r < 4; ++r) acc[i][j][r] = 0.f;

    const short* Ag = (const short*)A;
    const short* Bg = (const short*)BT;
    const int arow0 = tid >> 2;
    const int arow1 = (tid + 256) >> 2;
    const int acol = (tid & 3) * 8;

    const int fr = lane & 15;
    const int kg = (lane >> 4) * 8;

    for (int k0 = 0; k0 < K; k0 += 32) {
        gload_lds16(Ag + (size_t)(m0 + arow0) * K + k0 + acol, &As[tid * 8]);
        if (MI == 4)
            gload_lds16(Ag + (size_t)(m0 + arow1) * K + k0 + acol, &As[(tid + 256) * 8]);
        gload_lds16(Bg + (size_t)(n0 + arow0) * K + k0 + acol, &Bs[tid * 8]);
        gload_lds16(Bg + (size_t)(n0 + arow1) * K + k0 + acol, &Bs[(tid + 256) * 8]);
        __syncthreads();

        bf16x8_t af[MI], bq[4];
#pragma unroll
        for (int mi = 0; mi < MI; ++mi)
            af[mi] = *(const bf16x8_t*)&As[(wr * (MI * 16) + mi * 16 + fr) * 32 + kg];
#pragma unroll
        for (int ni = 0; ni < 4; ++ni)
            bq[ni] = *(const bf16x8_t*)&Bs[(wc * 64 + ni * 16 + fr) * 32 + kg];
#pragma unroll
        for (int mi = 0; mi < MI; ++mi)
#pragma unroll
            for (int ni = 0; ni < 4; ++ni)
                acc[mi][ni] = __builtin_amdgcn_mfma_f32_16x16x32_bf16(af[mi], bq[ni], acc[mi][ni], 0, 0, 0);
        __syncthreads();
    }

    float bvec[4];
    if (BIAS) {
#pragma unroll
        for (int ni = 0; ni < 4; ++ni) bvec[ni] = bias[n0 + wc * 64 + ni * 16 + fr];
    }
    const int rbase = m0 + wr * (MI * 16) + (lane >> 4) * 4;
    const int cbase = n0 + wc * 64 + fr;
#pragma unroll
    for (int mi = 0; mi < MI; ++mi) {
#pragma unroll
        for (int ni = 0; ni < 4; ++ni) {
#pragma unroll
            for (int r = 0; r < 4; ++r) {
                int row = rbase + mi * 16 + r;
                int col = cbase + ni * 16;
                float v = acc[mi][ni][r];
                if (BIAS) v += bvec[ni];
                if (RELU) v = fmaxf(v, 0.f);
                size_t off = (size_t)row * N + col;
                if (OBF16) {
                    ((__hip_bfloat16*)Cv)[off] = __float2bfloat16(v);
                } else {
                    float* Cf = (float*)Cv;
                    if (ACCUM) Cf[off] += v; else Cf[off] = v;
                }
            }
        }
    }
}

// ---------------- 256x256 8-phase MFMA GEMM (proven r5/r8 form, BK=64) ---------
__device__ __forceinline__ bf16x8_t ldsrd256(const short* base, int row, int colb) {
    return *(const bf16x8_t*)((const char*)base + ((row << 7) + (colb ^ ((row & 7) << 4))));
}

template <bool BIAS, bool RELU, bool OBF16, bool LSE>
__global__ __launch_bounds__(512, 2) void mgemm256_k(const __hip_bfloat16* __restrict__ A,
                                                     const __hip_bfloat16* __restrict__ BT,
                                                     const float* __restrict__ bias,
                                                     void* __restrict__ Cv,
                                                     int M, int N, int K,
                                                     int ntn, int npart,
                                                     float2* __restrict__ partials) {
    __shared__ __align__(16) short lds[2][2][2][8192];   // [buf][A/B][half][128*64]

    const int nwg = gridDim.x;
    const int bid = blockIdx.x;
    const int cpx = nwg >> 3;
    const int swz = (bid & 7) * cpx + (bid >> 3);
    const int tm = swz / ntn, tn = swz - tm * ntn;
    const int m0 = tm * 256, n0 = tn * 256;

    const int tid = threadIdx.x;
    const int lane = tid & 63;
    const int wave = tid >> 6;
    const int wm = wave >> 2;       // 0..1
    const int wn = wave & 3;        // 0..3
    const int fr = lane & 15;
    const int hi4 = lane >> 4;

    const short* Ag = (const short*)A;
    const short* Bg = (const short*)BT;
    const int nt = K >> 6;          // 12

    auto stage_half = [&](const short* g, int grow0, int k0, short* lbase) {
#pragma unroll
        for (int sub = 0; sub < 2; ++sub) {
            int d = sub * 8192 + tid * 16;
            int row = d >> 7;
            int cb = d & 127;
            int col = (cb ^ ((row & 7) << 4)) >> 1;
            gload_lds16(g + (size_t)(grow0 + row) * K + k0 + col, (char*)lbase + d);
        }
    };

    f32x4_t acc[2][2][4][2];
#pragma unroll
    for (int ah = 0; ah < 2; ++ah)
#pragma unroll
        for (int s = 0; s < 2; ++s)
#pragma unroll
            for (int mi = 0; mi < 4; ++mi)
#pragma unroll
                for (int ni = 0; ni < 2; ++ni)
#pragma unroll
                    for (int r = 0; r < 4; ++r) acc[ah][s][mi][ni][r] = 0.f;

    stage_half(Ag, m0 + 0,   0,  &lds[0][0][0][0]);
    stage_half(Bg, n0 + 0,   0,  &lds[0][1][0][0]);
    stage_half(Ag, m0 + 128, 0,  &lds[0][0][1][0]);
    stage_half(Bg, n0 + 128, 0,  &lds[0][1][1][0]);
    stage_half(Ag, m0 + 0,   64, &lds[1][0][0][0]);
    stage_half(Bg, n0 + 0,   64, &lds[1][1][0][0]);
    asm volatile("s_waitcnt vmcnt(4)" ::: "memory");
    __builtin_amdgcn_s_barrier();

    for (int t = 0; t < nt; ++t) {
        const int c = t & 1, o = c ^ 1;
        bf16x8_t a[4][2];
#pragma unroll
        for (int p = 0; p < 4; ++p) {
            const int ah = p >> 1, s = p & 1;
            if (s == 0) {
#pragma unroll
                for (int mi = 0; mi < 4; ++mi)
#pragma unroll
                    for (int kk = 0; kk < 2; ++kk)
                        a[mi][kk] = ldsrd256(&lds[c][0][ah][0],
                                             wm * 64 + mi * 16 + fr, kk * 64 + hi4 * 16);
            }
            bf16x8_t b[2][2];
#pragma unroll
            for (int ni = 0; ni < 2; ++ni)
#pragma unroll
                for (int kk = 0; kk < 2; ++kk)
                    b[ni][kk] = ldsrd256(&lds[c][1][s][0],
                                         wn * 32 + ni * 16 + fr, kk * 64 + hi4 * 16);
            if (p == 0 && t + 1 < nt) stage_half(Ag, m0 + 128, (t + 1) * 64, &lds[o][0][1][0]);
            if (p == 1 && t + 1 < nt) stage_half(Bg, n0 + 128, (t + 1) * 64, &lds[o][1][1][0]);
            if (p == 2 && t + 2 < nt) stage_half(Ag, m0 + 0,   (t + 2) * 64, &lds[c][0][0][0]);
            if (p == 3 && t + 2 < nt) stage_half(Bg, n0 + 0,   (t + 2) * 64, &lds[c][1][0][0]);
            if (p == 3) {
                if (t < nt - 2)       asm volatile("s_waitcnt vmcnt(4)" ::: "memory");
                else if (t == nt - 2) asm volatile("s_waitcnt vmcnt(0)" ::: "memory");
            }
            __builtin_amdgcn_s_barrier();
            asm volatile("s_waitcnt lgkmcnt(0)" ::: "memory");
            __builtin_amdgcn_sched_barrier(0);
            __builtin_amdgcn_s_setprio(1);
#pragma unroll
            for (int mi = 0; mi < 4; ++mi)
#pragma unroll
                for (int ni = 0; ni < 2; ++ni)
#pragma unroll
                    for (int kk = 0; kk < 2; ++kk)
                        acc[ah][s][mi][ni] = __builtin_amdgcn_mfma_f32_16x16x32_bf16(
                            a[mi][kk], b[ni][kk], acc[ah][s][mi][ni], 0, 0, 0);
            __builtin_amdgcn_s_setprio(0);
            __builtin_amdgcn_s_barrier();
        }
    }

    float bv[2][2];
    if (BIAS) {
#pragma unroll
        for (int s = 0; s < 2; ++s)
#pragma unroll
            for (int ni = 0; ni < 2; ++ni)
                bv[s][ni] = bias[n0 + s * 128 + wn * 32 + ni * 16 + fr];
    }
    float2* red = (float2*)&lds[0][0][0][0];
#pragma unroll
    for (int ah = 0; ah < 2; ++ah) {
#pragma unroll
        for (int mi = 0; mi < 4; ++mi) {
#pragma unroll
            for (int r = 0; r < 4; ++r) {
                const int rb = ah * 128 + wm * 64 + mi * 16 + hi4 * 4 + r;
                const size_t grow = (size_t)(m0 + rb);
                float v[2][2];
#pragma unroll
                for (int s = 0; s < 2; ++s)
#pragma unroll
                    for (int ni = 0; ni < 2; ++ni) {
                        float vv = acc[ah][s][mi][ni][r];
                        if (BIAS) vv += bv[s][ni];
                        if (RELU) vv = fmaxf(vv, 0.f);
                        v[s][ni] = vv;
                        size_t off = grow * N + n0 + s * 128 + wn * 32 + ni * 16 + fr;
                        if (OBF16) ((__hip_bfloat16*)Cv)[off] = __float2bfloat16(vv);
                        else       ((float*)Cv)[off] = vv;
                    }
                if (LSE) {
                    float mx = fmaxf(fmaxf(v[0][0], v[0][1]), fmaxf(v[1][0], v[1][1]));
#pragma unroll
                    for (int off2 = 1; off2 < 16; off2 <<= 1) mx = fmaxf(mx, __shfl_xor(mx, off2));
                    float sm = 0.f;
#pragma unroll
                    for (int s = 0; s < 2; ++s)
#pragma unroll
                        for (int ni = 0; ni < 2; ++ni) sm += __expf(v[s][ni] - mx);
#pragma unroll
                    for (int off2 = 1; off2 < 16; off2 <<= 1) sm += __shfl_xor(sm, off2);
                    if (fr == 0) red[rb * 4 + wn] = make_float2(mx, sm);
                }
            }
        }
    }
    if (LSE) {
        __syncthreads();
        if (tid < 256) {
            float2 p0 = red[tid * 4 + 0], p1 = red[tid * 4 + 1];
            float2 p2 = red[tid * 4 + 2], p3 = red[tid * 4 + 3];
            float M2 = fmaxf(fmaxf(p0.x, p1.x), fmaxf(p2.x, p3.x));
            float L2 = p0.y * __expf(p0.x - M2) + p1.y * __expf(p1.x - M2) +
                       p2.y * __expf(p2.x - M2) + p3.y * __expf(p3.x - M2);
            partials[(size_t)(m0 + tid) * npart + tn] = make_float2(M2, L2);
        }
    }
}

// ---------------- MFMA flash attention: swapped QK^T + T14 + T13 + T5 ----------
__global__ __launch_bounds__(256) void fattn_k(const __hip_bfloat16* __restrict__ qkv,
                                               __hip_bfloat16* __restrict__ o) {
    __shared__ short Ks[KVB * HS];
    __shared__ short Vt[HS * KVB];
    __shared__ short Pl[4 * 32 * KVB];

    const int bh = blockIdx.x;
    const int hh = bh % HH;
    const int bI = bh / HH;
    const int qt = (TT / QBLK - 1) - blockIdx.y;   // heavy tiles first
    const int q0 = qt * QBLK;

    const int tid = threadIdx.x;
    const int lane = tid & 63;
    const int wave = tid >> 6;
    const int fr = lane & 15;
    const int hi4 = lane >> 4;

    const size_t rowbase = (size_t)bI * TT;
    const int wq0 = q0 + wave * 32;

    bf16x8_t qf[2][2];
#pragma unroll
    for (int mi = 0; mi < 2; ++mi)
#pragma unroll
        for (int kc = 0; kc < 2; ++kc) {
            const short* src = (const short*)qkv +
                (rowbase + wq0 + mi * 16 + fr) * QS + hh * HS + kc * 32 + hi4 * 8;
            bf16x8_t v = *(const bf16x8_t*)src;
#pragma unroll
            for (int e = 0; e < 8; ++e) {
                float f = __uint_as_float(((unsigned)(unsigned short)v[e]) << 16) * 0.125f;
                v[e] = (short)(__float_as_uint(f) >> 16);
            }
            qf[mi][kc] = v;
        }

    f32x4_t oa[2][4];
    float m_r[2], l_r[2];
#pragma unroll
    for (int mi = 0; mi < 2; ++mi) {
        m_r[mi] = -INFINITY;
        l_r[mi] = 0.f;
#pragma unroll
        for (int nd = 0; nd < 4; ++nd)
#pragma unroll
            for (int r = 0; r < 4; ++r) oa[mi][nd][r] = 0.f;
    }

    const int skey = tid >> 2;
    const int sd0 = (tid & 3) * 16;
    const int niter = 2 * (qt + 1);

    uint4 ka, kb2, va, vb2;
    {
        const short* kg = (const short*)qkv + (rowbase + skey) * QS + EE + hh * HS + sd0;
        ka = *(const uint4*)kg; kb2 = *(const uint4*)(kg + 8);
        const short* vg = (const short*)qkv + (rowbase + skey) * QS + 2 * EE + hh * HS + sd0;
        va = *(const uint4*)vg; vb2 = *(const uint4*)(vg + 8);
    }

    for (int it = 0; it < niter; ++it) {
        __syncthreads();
        {
            const int rs = (skey & 7) << 4;
            char* kbp = (char*)Ks;
            *(uint4*)(kbp + ((skey * 128 + sd0 * 2) ^ rs)) = ka;
            *(uint4*)(kbp + ((skey * 128 + sd0 * 2 + 16) ^ rs)) = kb2;

            char* vbp = (char*)Vt;
            const short* vs0 = (const short*)&va;
#pragma unroll
            for (int e = 0; e < 8; ++e) {
                int dd = sd0 + e;
                *(short*)(vbp + ((dd * 128 + skey * 2) ^ ((dd & 7) << 4))) = vs0[e];
            }
            const short* vs1 = (const short*)&vb2;
#pragma unroll
            for (int e = 0; e < 8; ++e) {
                int dd = sd0 + 8 + e;
                *(short*)(vbp + ((dd * 128 + skey * 2) ^ ((dd & 7) << 4))) = vs1[e];
            }
        }
        __syncthreads();

        if (it + 1 < niter) {
            const int kvn = (it + 1) * KVB;
            const short* kg = (const short*)qkv + (rowbase + kvn + skey) * QS + EE + hh * HS + sd0;
            ka = *(const uint4*)kg; kb2 = *(const uint4*)(kg + 8);
            const short* vg = (const short*)qkv + (rowbase + kvn + skey) * QS + 2 * EE + hh * HS + sd0;
            va = *(const uint4*)vg; vb2 = *(const uint4*)(vg + 8);
        }

        const int kv0 = it * KVB;

        f32x4_t sa[2][4];
#pragma unroll
        for (int mi = 0; mi < 2; ++mi)
#pragma unroll
            for (int ni = 0; ni < 4; ++ni)
#pragma unroll
                for (int r = 0; r < 4; ++r) sa[mi][ni][r] = 0.f;
        __builtin_amdgcn_s_setprio(1);
#pragma unroll
        for (int kc = 0; kc < 2; ++kc) {
            bf16x8_t kf[4];
#pragma unroll
            for (int ni = 0; ni < 4; ++ni) {
                int krow = ni * 16 + fr;
                kf[ni] = *(const bf16x8_t*)((char*)Ks +
                    ((krow * 128 + (kc * 32 + hi4 * 8) * 2) ^ ((krow & 7) << 4)));
            }
#pragma unroll
            for (int mi = 0; mi < 2; ++mi)
#pragma unroll
                for (int ni = 0; ni < 4; ++ni)
                    sa[mi][ni] = __builtin_amdgcn_mfma_f32_16x16x32_bf16(kf[ni], qf[mi][kc], sa[mi][ni], 0, 0, 0);
        }
        __builtin_amdgcn_s_setprio(0);

        if (kv0 + KVB - 1 > wq0) {
#pragma unroll
            for (int mi = 0; mi < 2; ++mi) {
                int qrow = wq0 + mi * 16 + fr;
#pragma unroll
                for (int ni = 0; ni < 4; ++ni)
#pragma unroll
                    for (int r = 0; r < 4; ++r) {
                        int key = kv0 + ni * 16 + hi4 * 4 + r;
                        if (key > qrow) sa[mi][ni][r] = -1e30f;
                    }
            }
        }

        char* Pw = (char*)Pl + wave * 4096;
#pragma unroll
        for (int mi = 0; mi < 2; ++mi) {
            float mx = sa[mi][0][0];
#pragma unroll
            for (int ni = 0; ni < 4; ++ni)
#pragma unroll
                for (int r = 0; r < 4; ++r) mx = fmaxf(mx, sa[mi][ni][r]);
            mx = fmaxf(mx, __shfl_xor(mx, 16));
            mx = fmaxf(mx, __shfl_xor(mx, 32));
            // T13 defer-max: skip rescale while tile max stays within 8 of running max
            if (!__all(mx <= m_r[mi] + 8.0f)) {
                float mnew = fmaxf(m_r[mi], mx);
                float al = __expf(m_r[mi] - mnew);
                m_r[mi] = mnew;
                l_r[mi] *= al;
#pragma unroll
                for (int r = 0; r < 4; ++r) {
                    float a_r = __shfl(al, hi4 * 4 + r);
#pragma unroll
                    for (int nd = 0; nd < 4; ++nd) oa[mi][nd][r] *= a_r;
                }
            }
            float ps = 0.f;
#pragma unroll
            for (int ni = 0; ni < 4; ++ni) {
#pragma unroll
                for (int r = 0; r < 4; ++r) {
                    float p = __expf(sa[mi][ni][r] - m_r[mi]);
                    sa[mi][ni][r] = p;
                    ps += p;
                }
                uint2 pw;
                pw.x = pk2bf(sa[mi][ni][0], sa[mi][ni][1]);
                pw.y = pk2bf(sa[mi][ni][2], sa[mi][ni][3]);
                int prow = mi * 16 + fr;
                int cb = ni * 32 + hi4 * 8;
                *(uint2*)(Pw + ((prow * 128 + cb) ^ ((prow & 7) << 4))) = pw;
            }
            ps += __shfl_xor(ps, 16);
            ps += __shfl_xor(ps, 32);
            l_r[mi] += ps;
        }

        __builtin_amdgcn_s_setprio(1);
#pragma unroll
        for (int kc = 0; kc < 2; ++kc) {
            bf16x8_t pf[2], vf[4];
#pragma unroll
            for (int mi = 0; mi < 2; ++mi) {
                int prow = mi * 16 + fr;
                pf[mi] = *(const bf16x8_t*)(Pw +
                    ((prow * 128 + (kc * 32 + hi4 * 8) * 2) ^ ((prow & 7) << 4)));
            }
#pragma unroll
            for (int nd = 0; nd < 4; ++nd) {
                int vrow = nd * 16 + fr;
                vf[nd] = *(const bf16x8_t*)((char*)Vt +
                    ((vrow * 128 + (kc * 32 + hi4 * 8) * 2) ^ ((vrow & 7) << 4)));
            }
#pragma unroll
            for (int mi = 0; mi < 2; ++mi)
#pragma unroll
                for (int nd = 0; nd < 4; ++nd)
                    oa[mi][nd] = __builtin_amdgcn_mfma_f32_16x16x32_bf16(pf[mi], vf[nd], oa[mi][nd], 0, 0, 0);
        }
        __builtin_amdgcn_s_setprio(0);
    }

#pragma unroll
    for (int mi = 0; mi < 2; ++mi)
#pragma unroll
        for (int r = 0; r < 4; ++r) {
            float lr = __shfl(l_r[mi], hi4 * 4 + r);
            float inv = 1.0f / lr;
            int row = wq0 + mi * 16 + hi4 * 4 + r;
            __hip_bfloat16* orow = o + (rowbase + row) * EE + hh * HS;
#pragma unroll
            for (int nd = 0; nd < 4; ++nd)
                orow[nd * 16 + fr] = __float2bfloat16(oa[mi][nd][r] * inv);
        }
}

// ---------------- loss: merge per-block LSE partials ----------------
__global__ __launch_bounds__(256) void rowloss2_k(const float2* __restrict__ partials,
                                                  const float* __restrict__ logits,
                                                  const int* __restrict__ targets,
                                                  float* __restrict__ rowloss, int ntn) {
    __shared__ float red[4];
    int row = blockIdx.x;
    int tid = threadIdx.x;
    float m = -INFINITY, l = 0.f;
    if (tid < ntn) {
        float2 p = partials[(size_t)row * ntn + tid];
        m = p.x; l = p.y;
    }
    float mg = block_max256(m, red);
    float s = (tid < ntn) ? l * __expf(m - mg) : 0.f;
    s = block_sum256(s, red);
    if (tid == 0)
        rowloss[row] = mg + logf(s) - logits[(size_t)row * VV + targets[row]];
}

__global__ __launch_bounds__(256) void loss_final_k(const float* __restrict__ rowloss,
                                                    float* __restrict__ out) {
    __shared__ float red[4];
    float s = 0.f;
    for (int i = threadIdx.x; i < MROWS; i += 256) s += rowloss[i];
    s = block_sum256(s, red);
    if (threadIdx.x == 0) out[0] = s * (1.0f / MROWS);
}

// ---------------- launcher ----------------
extern "C" void kernel_launch(void* const* d_in, const int* in_sizes, int n_in,
                              void* d_out, int out_size, void* d_ws, size_t ws_size,
                              hipStream_t stream) {
    const int* idx      = (const int*)d_in[0];
    const int* targets  = (const int*)d_in[1];
    const float* tok    = (const float*)d_in[2];
    const float* pos    = (const float*)d_in[3];
    const float* Wq     = (const float*)d_in[4];
    const float* Wk     = (const float*)d_in[5];
    const float* Wv     = (const float*)d_in[6];
    const float* Wp     = (const float*)d_in[7];
    const float* bp     = (const float*)d_in[8];
    const float* W1     = (const float*)d_in[9];
    const float* b1     = (const float*)d_in[10];
    const float* W2     = (const float*)d_in[11];
    const float* b2     = (const float*)d_in[12];
    const float* ln1_g  = (const float*)d_in[13];
    const float* ln1_b  = (const float*)d_in[14];
    const float* ln2_g  = (const float*)d_in[15];
    const float* ln2_b  = (const float*)d_in[16];
    const float* lnf_g  = (const float*)d_in[17];
    const float* lnf_b  = (const float*)d_in[18];
    const float* Wlm    = (const float*)d_in[19];
    const float* blm    = (const float*)d_in[20];

    float* out = (float*)d_out;

    // ---- workspace carve ----
    char* w = (char*)d_ws;
    float* x = (float*)w;                             w += (size_t)MROWS * EE * 4;
    __hip_bfloat16* hbf = (__hip_bfloat16*)w;         w += (size_t)MROWS * EE * 2;
    __hip_bfloat16* qkv = (__hip_bfloat16*)w;         w += (size_t)MROWS * QS * 2;
    __hip_bfloat16* obf = (__hip_bfloat16*)w;         w += (size_t)MROWS * EE * 2;
    __hip_bfloat16* ff1 = (__hip_bfloat16*)w;         w += (size_t)MROWS * FFD * 2;
    float2* partials = (float2*)ff1;                  // aliases ff1: dead by LM-head time
    __hip_bfloat16* wlmT = (__hip_bfloat16*)w;        w += (size_t)VV * EE * 2;
    float* rowloss = (float*)w;                       w += (size_t)MROWS * 4 + 256;
    __hip_bfloat16* wbase = (__hip_bfloat16*)w;       // layer weights from here

    const size_t base_used = (size_t)(w - (char*)d_ws);
    const size_t per_layer_w = ((size_t)QS * EE + (size_t)EE * EE +
                                (size_t)FFD * EE + (size_t)EE * FFD) * 2;
    const bool hoist = ws_size >= base_used + per_layer_w * LAYERS;
    const int nlw = hoist ? LAYERS : 1;

    __hip_bfloat16* qkvwT = wbase;
    __hip_bfloat16* wpT   = qkvwT + (size_t)nlw * QS * EE;
    __hip_bfloat16* w1T   = wpT   + (size_t)nlw * EE * EE;
    __hip_bfloat16* w2T   = w1T   + (size_t)nlw * FFD * EE;

    dim3 blk(256);

    embed4_k<<<MROWS / 4, blk, 0, stream>>>(idx, tok, pos, x);

    if (hoist) {
        tconv_b_k<<<dim3(EE / 32, EE / 32, LAYERS), blk, 0, stream>>>(
            Wq, qkvwT, EE, EE, (size_t)EE * EE, (size_t)QS * EE);
        tconv_b_k<<<dim3(EE / 32, EE / 32, LAYERS), blk, 0, stream>>>(
            Wk, qkvwT + (size_t)EE * EE, EE, EE, (size_t)EE * EE, (size_t)QS * EE);
        tconv_b_k<<<dim3(EE / 32, EE / 32, LAYERS), blk, 0, stream>>>(
            Wv, qkvwT + (size_t)2 * EE * EE, EE, EE, (size_t)EE * EE, (size_t)QS * EE);
        tconv_b_k<<<dim3(EE / 32, EE / 32, LAYERS), blk, 0, stream>>>(
            Wp, wpT, EE, EE, (size_t)EE * EE, (size_t)EE * EE);
        tconv_b_k<<<dim3(FFD / 32, EE / 32, LAYERS), blk, 0, stream>>>(
            W1, w1T, EE, FFD, (size_t)EE * FFD, (size_t)FFD * EE);
        tconv_b_k<<<dim3(EE / 32, FFD / 32, LAYERS), blk, 0, stream>>>(
            W2, w2T, FFD, EE, (size_t)FFD * EE, (size_t)EE * FFD);
    }
    tconv_b_k<<<dim3(VV / 32, EE / 32, 1), blk, 0, stream>>>(Wlm, wlmT, EE, VV, 0, 0);

    for (int l = 0; l < LAYERS; ++l) {
        __hip_bfloat16* qkvwT_l = qkvwT + (hoist ? (size_t)l * QS * EE : 0);
        __hip_bfloat16* wpT_l   = wpT   + (hoist ? (size_t)l * EE * EE : 0);
        __hip_bfloat16* w1T_l   = w1T   + (hoist ? (size_t)l * FFD * EE : 0);
        __hip_bfloat16* w2T_l   = w2T   + (hoist ? (size_t)l * EE * FFD : 0);
        if (!hoist) {
            tconv_b_k<<<dim3(EE / 32, EE / 32, 1), blk, 0, stream>>>(
                Wq + (size_t)l * EE * EE, qkvwT_l, EE, EE, 0, 0);
            tconv_b_k<<<dim3(EE / 32, EE / 32, 1), blk, 0, stream>>>(
                Wk + (size_t)l * EE * EE, qkvwT_l + (size_t)EE * EE, EE, EE, 0, 0);
            tconv_b_k<<<dim3(EE / 32, EE / 32, 1), blk, 0, stream>>>(
                Wv + (size_t)l * EE * EE, qkvwT_l + (size_t)2 * EE * EE, EE, EE, 0, 0);
            tconv_b_k<<<dim3(EE / 32, EE / 32, 1), blk, 0, stream>>>(
                Wp + (size_t)l * EE * EE, wpT_l, EE, EE, 0, 0);
            tconv_b_k<<<dim3(FFD / 32, EE / 32, 1), blk, 0, stream>>>(
                W1 + (size_t)l * EE * FFD, w1T_l, EE, FFD, 0, 0);
            tconv_b_k<<<dim3(EE / 32, FFD / 32, 1), blk, 0, stream>>>(
                W2 + (size_t)l * FFD * EE, w2T_l, FFD, EE, 0, 0);
        }

        ln4_k<<<MROWS / 4, blk, 0, stream>>>(x, ln1_g + l * EE, ln1_b + l * EE, hbf);
        mgemm_k<false, false, false, true, 4><<<dim3((MROWS / 128) * (QS / 128)), blk, 0, stream>>>(
            hbf, qkvwT_l, nullptr, qkv, MROWS, QS, EE, QS / 128);
        fattn_k<<<dim3(BB * HH, TT / QBLK), blk, 0, stream>>>(qkv, obf);
        mgemm_k<true, false, true, false, 2><<<dim3((MROWS / 64) * (EE / 128)), blk, 0, stream>>>(
            obf, wpT_l, bp + l * EE, x, MROWS, EE, EE, EE / 128);
        ln4_k<<<MROWS / 4, blk, 0, stream>>>(x, ln2_g + l * EE, ln2_b + l * EE, hbf);
        mgemm_k<true, true, false, true, 4><<<dim3((MROWS / 128) * (FFD / 128)), blk, 0, stream>>>(
            hbf, w1T_l, b1 + l * FFD, ff1, MROWS, FFD, EE, FFD / 128);
        mgemm_k<true, false, true, false, 2><<<dim3((MROWS / 64) * (EE / 128)), blk, 0, stream>>>(
            ff1, w2T_l, b2 + l * EE, x, MROWS, EE, FFD, EE / 128);
    }

    ln4_k<<<MROWS / 4, blk, 0, stream>>>(x, lnf_g, lnf_b, hbf);
    // LM head: proven 256x256 8-phase BK=64 kernel + fused LSE partials
    mgemm256_k<true, false, false, true><<<dim3((MROWS / 256) * (VV / 256)), dim3(512), 0, stream>>>(
        hbf, wlmT, blm, out, MROWS, VV, EE, VV / 256, NPART, partials);

    rowloss2_k<<<MROWS, blk, 0, stream>>>(partials, out, targets, rowloss, NPART);
    loss_final_k<<<1, blk, 0, stream>>>(rowloss, out + (size_t)MROWS * VV);
}